// Round 1
// baseline (1123.243 us; speedup 1.0000x reference)
//
#include <hip/hip_runtime.h>
#include <hip/hip_bf16.h>

typedef unsigned short u16;
typedef unsigned int   u32;
typedef unsigned long long uptr;
typedef short bf16x8 __attribute__((ext_vector_type(8)));
typedef float f32x4  __attribute__((ext_vector_type(4)));

#define PIMG 9216           // 96*96 pixels per image
#define HH 96
#define WW 96
#define MTOT 36864          // 4 * 9216 global pixel rows
// 256/(512*sqrt(96)) = 0.5/sqrt(96)
#define SCALE 0.05103103630798288f

__device__ __forceinline__ u16 f2b(float f) {          // fp32 -> bf16 RNE
  u32 u = __float_as_uint(f);
  u += 0x7fffu + ((u >> 16) & 1u);
  return (u16)(u >> 16);
}
__device__ __forceinline__ float bl(u32 u) { return __uint_as_float(u << 16); }
__device__ __forceinline__ float bh(u32 u) { return __uint_as_float(u & 0xffff0000u); }

__device__ __forceinline__ void gl2lds16(const void* g, void* l) {
  __builtin_amdgcn_global_load_lds(
      (const __attribute__((address_space(1))) void*)(uptr)g,
      (__attribute__((address_space(3))) void*)(uptr)l, 16, 0, 0);
}

// ---------------------------------------------------------------------------
// fp32 [C][P] -> bf16 [P][C] transpose+convert (per batch in blockIdx.z)
// ---------------------------------------------------------------------------
__global__ void __launch_bounds__(256)
transpose_cvt(const float* __restrict__ src, u16* __restrict__ dst) {
  __shared__ float tile[64][33];
  const int tx = threadIdx.x, ty = threadIdx.y;      // (32,8)
  const int p0 = blockIdx.x * 32, c0 = blockIdx.y * 64;
  const float* s = src + (size_t)blockIdx.z * 1024 * PIMG;
  u16* d = dst + (size_t)blockIdx.z * PIMG * 1024;
#pragma unroll
  for (int i = 0; i < 8; ++i) {
    int c = ty + i * 8;
    tile[c][tx] = s[(size_t)(c0 + c) * PIMG + p0 + tx];
  }
  __syncthreads();
#pragma unroll
  for (int i = 0; i < 4; ++i) {
    int p = ty + i * 8;
    u32 lo = f2b(tile[2 * tx][p]);
    u32 hi = f2b(tile[2 * tx + 1][p]);
    *(u32*)(d + (size_t)(p0 + p) * 1024 + c0 + 2 * tx) = lo | (hi << 16);
  }
}

// fp32 -> bf16 pairwise convert (weights)
__global__ void __launch_bounds__(256)
cvt_pairs(const float* __restrict__ s, u16* __restrict__ d, int n2) {
  int i = blockIdx.x * blockDim.x + threadIdx.x;
  if (i < n2) {
    float2 v = ((const float2*)s)[i];
    ((u32*)d)[i] = (u32)f2b(v.x) | ((u32)f2b(v.y) << 16);
  }
}

// ---------------------------------------------------------------------------
// GEMM: C[p][o] = sum_c A[p][c] * B[o][c]   (A row-major [M][K], B [N][K])
// 128x128 tile, BK=64, 4 waves, 4x4 16x16x32 bf16 MFMA subtiles per wave.
// global_load_lds w=16 staging; XOR chunk swizzle on the GLOBAL side so LDS
// stays linear (m104 caveat) while ds_read_b128 fragment reads stay
// conflict-optimal.
// EPI 0: bf16 out + bias (split select between bias0/bias1)
// EPI 1: fp32 out = acc + bias0 + xres (residual), out/res layout [b][N][PIMG]
// ---------------------------------------------------------------------------
template <int EPI>
__global__ void __launch_bounds__(256)
gemm_bf16(const u16* __restrict__ A, const u16* __restrict__ B, int K,
          u16* __restrict__ outb, int ldo,
          const float* __restrict__ bias0, const float* __restrict__ bias1,
          int split, float* __restrict__ outf, const float* __restrict__ xres) {
  __shared__ u16 lds[2 * 128 * 64];                  // 32 KB
  u16* Alds = lds;
  u16* Blds = lds + 128 * 64;

  const int tid = threadIdx.x;
  const int wave = tid >> 6, lane = tid & 63;
  const int quad = lane >> 4, col = lane & 15;
  const int wr = wave >> 1, wc = wave & 1;
  const int m0 = blockIdx.y * 128, n0 = blockIdx.x * 128;

  f32x4 acc[4][4] = {};

  int srow[4], skc[4];
#pragma unroll
  for (int i = 0; i < 4; ++i) {
    int c = i * 256 + tid;
    srow[i] = c >> 3;
    skc[i] = (c & 7) ^ (srow[i] & 7);                // swizzled source chunk
  }

  for (int k0 = 0; k0 < K; k0 += 64) {
    __syncthreads();
#pragma unroll
    for (int i = 0; i < 4; ++i)
      gl2lds16(A + (size_t)(m0 + srow[i]) * K + k0 + skc[i] * 8,
               Alds + (i * 256 + wave * 64) * 8);
#pragma unroll
    for (int i = 0; i < 4; ++i)
      gl2lds16(B + (size_t)(n0 + srow[i]) * K + k0 + skc[i] * 8,
               Blds + (i * 256 + wave * 64) * 8);
    __syncthreads();
#pragma unroll
    for (int ks = 0; ks < 2; ++ks) {
      bf16x8 af[4], bfr[4];
#pragma unroll
      for (int mt = 0; mt < 4; ++mt) {
        int row = wr * 64 + mt * 16 + col;
        int pos = (ks * 4 + quad) ^ (row & 7);
        af[mt] = *(const bf16x8*)(Alds + row * 64 + pos * 8);
      }
#pragma unroll
      for (int nt = 0; nt < 4; ++nt) {
        int row = wc * 64 + nt * 16 + col;
        int pos = (ks * 4 + quad) ^ (row & 7);
        bfr[nt] = *(const bf16x8*)(Blds + row * 64 + pos * 8);
      }
#pragma unroll
      for (int mt = 0; mt < 4; ++mt)
#pragma unroll
        for (int nt = 0; nt < 4; ++nt)
          acc[mt][nt] = __builtin_amdgcn_mfma_f32_16x16x32_bf16(
              af[mt], bfr[nt], acc[mt][nt], 0, 0, 0);
    }
  }

  if (EPI == 0) {
#pragma unroll
    for (int nt = 0; nt < 4; ++nt) {
      int n = n0 + wc * 64 + nt * 16 + col;
      float bv = (n < split) ? bias0[n] : bias1[n - split];
#pragma unroll
      for (int mt = 0; mt < 4; ++mt) {
        int mb = m0 + wr * 64 + mt * 16 + quad * 4;
#pragma unroll
        for (int r = 0; r < 4; ++r)
          outb[(size_t)(mb + r) * ldo + n] = f2b(acc[mt][nt][r] + bv);
      }
    }
  } else {
    int b = m0 / PIMG;                               // tile never crosses image
    int pb = m0 - b * PIMG + wr * 64;
    const float* xr = xres + (size_t)b * 1024 * PIMG;
    float* op = outf + (size_t)b * 1024 * PIMG;
#pragma unroll
    for (int nt = 0; nt < 4; ++nt) {
      int n = n0 + wc * 64 + nt * 16 + col;
      float bv = bias0[n];
#pragma unroll
      for (int mt = 0; mt < 4; ++mt) {
        int p = pb + mt * 16 + quad * 4;
        const float4 xv = *(const float4*)(xr + (size_t)n * PIMG + p);
        float4 o;
        o.x = acc[mt][nt][0] + bv + xv.x;
        o.y = acc[mt][nt][1] + bv + xv.y;
        o.z = acc[mt][nt][2] + bv + xv.z;
        o.w = acc[mt][nt][3] + bv + xv.w;
        *(float4*)(op + (size_t)n * PIMG + p) = o;
      }
    }
  }
}

// ---------------------------------------------------------------------------
// Correlation: scores[p][q] = SCALE * dot(theta[p], phi[p+off_q]) (0 if OOB —
// zeros must still参加 softmax, done in assemble). 3 pixels per 256-thr block.
// theta: [M][512] bf16; phi = gphi columns 512..1023 of [M][1024].
// ---------------------------------------------------------------------------
__global__ void __launch_bounds__(256)
corr_kernel(const u16* __restrict__ theta, const u16* __restrict__ gphi,
            float* __restrict__ scores) {
  __shared__ u16 th[3 * 512];
  const int tid = threadIdx.x;
  const int p0 = blockIdx.x * 3;
  if (tid < 192) {
    int row = tid >> 6, c = tid & 63;
    *(uint4*)&th[row * 512 + c * 8] =
        *(const uint4*)(theta + (size_t)(p0 + row) * 512 + c * 8);
  }
  __syncthreads();
  if (tid < 243) {
    int pl = tid / 81;
    int q = tid - pl * 81;
    int dy = q / 9 - 4;
    int dx = q - (q / 9) * 9 - 4;
    int p = p0 + pl;
    int pim = p % PIMG;
    int h = pim / WW, w = pim - (pim / WW) * WW;
    float s = 0.f;
    if ((unsigned)(h + dy) < HH && (unsigned)(w + dx) < WW) {
      const u16* pr = gphi + (size_t)(p + dy * WW + dx) * 1024 + 512;
      const u16* tr = th + pl * 512;
      float a0 = 0.f, a1 = 0.f;
#pragma unroll 8
      for (int i = 0; i < 64; ++i) {
        uint4 av = *(const uint4*)(tr + i * 8);
        uint4 bv = *(const uint4*)(pr + i * 8);
        a0 += bl(av.x) * bl(bv.x) + bh(av.x) * bh(bv.x) +
              bl(av.y) * bl(bv.y) + bh(av.y) * bh(bv.y);
        a1 += bl(av.z) * bl(bv.z) + bh(av.z) * bh(bv.z) +
              bl(av.w) * bl(bv.w) + bh(av.w) * bh(bv.w);
      }
      s = (a0 + a1) * SCALE;
    }
    scores[(size_t)p * 81 + q] = s;
  }
}

// ---------------------------------------------------------------------------
// Assemble + softmax: one wave per pixel. y[p][c] = sum_q softmax(s)[q] *
// g[p+off_q][c]; g = gphi columns 0..511. OOB q: score 0 participates in
// softmax, g contribution skipped (zero pad).
// ---------------------------------------------------------------------------
__global__ void __launch_bounds__(256)
assemble_kernel(const float* __restrict__ scores, const u16* __restrict__ gphi,
                u16* __restrict__ y) {
  __shared__ float wl[4][81];
  const int tid = threadIdx.x;
  const int wave = tid >> 6, lane = tid & 63;
  const int p = blockIdx.x * 4 + wave;
  const float* sp = scores + (size_t)p * 81;
  float v0 = sp[lane];
  float v1 = (lane < 17) ? sp[64 + lane] : -1e30f;
  float mx = fmaxf(v0, v1);
#pragma unroll
  for (int off = 32; off > 0; off >>= 1) mx = fmaxf(mx, __shfl_xor(mx, off));
  float e0 = __expf(v0 - mx);
  float e1 = (lane < 17) ? __expf(v1 - mx) : 0.f;
  float sm = e0 + e1;
#pragma unroll
  for (int off = 32; off > 0; off >>= 1) sm += __shfl_xor(sm, off);
  float inv = 1.0f / sm;
  wl[wave][lane] = e0 * inv;
  if (lane < 17) wl[wave][64 + lane] = e1 * inv;
  __syncthreads();

  int pim = p % PIMG;
  int h = pim / WW, w = pim - (pim / WW) * WW;
  float acc[8] = {0, 0, 0, 0, 0, 0, 0, 0};
  for (int dy = -4; dy <= 4; ++dy) {
    bool vy = (unsigned)(h + dy) < HH;
#pragma unroll
    for (int dx = -4; dx <= 4; ++dx) {
      if (vy && (unsigned)(w + dx) < WW) {
        int q = (dy + 4) * 9 + (dx + 4);
        float wq = wl[wave][q];
        uint4 gv = *(const uint4*)(gphi + (size_t)(p + dy * WW + dx) * 1024 +
                                   lane * 8);
        acc[0] += wq * bl(gv.x); acc[1] += wq * bh(gv.x);
        acc[2] += wq * bl(gv.y); acc[3] += wq * bh(gv.y);
        acc[4] += wq * bl(gv.z); acc[5] += wq * bh(gv.z);
        acc[6] += wq * bl(gv.w); acc[7] += wq * bh(gv.w);
      }
    }
  }
  uint4 ov;
  ov.x = (u32)f2b(acc[0]) | ((u32)f2b(acc[1]) << 16);
  ov.y = (u32)f2b(acc[2]) | ((u32)f2b(acc[3]) << 16);
  ov.z = (u32)f2b(acc[4]) | ((u32)f2b(acc[5]) << 16);
  ov.w = (u32)f2b(acc[6]) | ((u32)f2b(acc[7]) << 16);
  *(uint4*)(y + (size_t)p * 512 + lane * 8) = ov;
}

// ---------------------------------------------------------------------------
extern "C" void kernel_launch(void* const* d_in, const int* in_sizes, int n_in,
                              void* d_out, int out_size, void* d_ws,
                              size_t ws_size, hipStream_t stream) {
  const float* x    = (const float*)d_in[0];
  const float* xref = (const float*)d_in[1];
  const float* w_g  = (const float*)d_in[2];
  const float* b_g  = (const float*)d_in[3];
  const float* w_th = (const float*)d_in[4];
  const float* b_th = (const float*)d_in[5];
  const float* w_ph = (const float*)d_in[6];
  const float* b_ph = (const float*)d_in[7];
  const float* w_o  = (const float*)d_in[8];
  const float* b_o  = (const float*)d_in[9];

  char* ws = (char*)d_ws;
  // big holds x_ref^T (bf16), then x^T, then y — sequential lifetimes.
  u16*   big    = (u16*)(ws);                        // 75,497,472 B
  u16*   gphi   = (u16*)(ws + 75497472);             // 75,497,472 B
  u16*   theta  = (u16*)(ws + 150994944);            // 37,748,736 B
  float* scores = (float*)(ws + 188743680);          // 11,943,936 B
  u16*   wgp    = (u16*)(ws + 200687616);            //  2,097,152 B
  u16*   wth    = (u16*)(ws + 202784768);            //  1,048,576 B
  u16*   wout   = (u16*)(ws + 203833344);            //  1,048,576 B
  // total 204,881,920 B

  // weights -> bf16 (w_g & w_phi stacked into one [1024][1024] B-operand)
  cvt_pairs<<<1024, 256, 0, stream>>>(w_g, wgp, 262144);
  cvt_pairs<<<1024, 256, 0, stream>>>(w_ph, wgp + 524288, 262144);
  cvt_pairs<<<1024, 256, 0, stream>>>(w_th, wth, 262144);
  cvt_pairs<<<1024, 256, 0, stream>>>(w_o, wout, 262144);

  dim3 tb(32, 8);
  // x_ref -> [p][c] bf16, then g|phi = xref^T x [w_g;w_phi]^T  (N=1024)
  transpose_cvt<<<dim3(288, 16, 4), tb, 0, stream>>>(xref, big);
  gemm_bf16<0><<<dim3(8, 288), 256, 0, stream>>>(big, wgp, 1024, gphi, 1024,
                                                 b_g, b_ph, 512, nullptr,
                                                 nullptr);
  // x -> [p][c] bf16 (reuses big), then theta (N=512)
  transpose_cvt<<<dim3(288, 16, 4), tb, 0, stream>>>(x, big);
  gemm_bf16<0><<<dim3(4, 288), 256, 0, stream>>>(big, wth, 1024, theta, 512,
                                                 b_th, b_th, 512, nullptr,
                                                 nullptr);

  corr_kernel<<<12288, 256, 0, stream>>>(theta, gphi, scores);
  assemble_kernel<<<9216, 256, 0, stream>>>(scores, gphi, big /* y */);

  // out = x + y x w_out^T + b_out   (fp32, fused residual epilogue)
  gemm_bf16<1><<<dim3(8, 288), 256, 0, stream>>>(big, wout, 512, nullptr, 0,
                                                 b_o, b_o, 1024, (float*)d_out,
                                                 x);
}

// Round 2
// 837.506 us; speedup vs baseline: 1.3412x; 1.3412x over previous
//
#include <hip/hip_runtime.h>
#include <hip/hip_bf16.h>

typedef unsigned short u16;
typedef unsigned int   u32;
typedef unsigned long long uptr;
typedef short bf16x8 __attribute__((ext_vector_type(8)));
typedef float f32x4  __attribute__((ext_vector_type(4)));

#define PIMG 9216           // 96*96 pixels per image
#define HH 96
#define WW 96
// 256/(512*sqrt(96)) = 0.5/sqrt(96)
#define SCALE 0.05103103630798288f

__device__ __forceinline__ u16 f2b(float f) {          // fp32 -> bf16 RNE
  u32 u = __float_as_uint(f);
  u += 0x7fffu + ((u >> 16) & 1u);
  return (u16)(u >> 16);
}
__device__ __forceinline__ float bl(u32 u) { return __uint_as_float(u << 16); }
__device__ __forceinline__ float bh(u32 u) { return __uint_as_float(u & 0xffff0000u); }

__device__ __forceinline__ void gl2lds16(const void* g, void* l) {
  __builtin_amdgcn_global_load_lds(
      (const __attribute__((address_space(1))) void*)(uptr)g,
      (__attribute__((address_space(3))) void*)(uptr)l, 16, 0, 0);
}

// ---------------------------------------------------------------------------
// fp32 [C][P] -> bf16 [P][C] transpose+convert (per batch in blockIdx.z)
// ---------------------------------------------------------------------------
__global__ void __launch_bounds__(256)
transpose_cvt(const float* __restrict__ src, u16* __restrict__ dst) {
  __shared__ float tile[64][33];
  const int tx = threadIdx.x, ty = threadIdx.y;      // (32,8)
  const int p0 = blockIdx.x * 32, c0 = blockIdx.y * 64;
  const float* s = src + (size_t)blockIdx.z * 1024 * PIMG;
  u16* d = dst + (size_t)blockIdx.z * PIMG * 1024;
#pragma unroll
  for (int i = 0; i < 8; ++i) {
    int c = ty + i * 8;
    tile[c][tx] = s[(size_t)(c0 + c) * PIMG + p0 + tx];
  }
  __syncthreads();
#pragma unroll
  for (int i = 0; i < 4; ++i) {
    int p = ty + i * 8;
    u32 lo = f2b(tile[2 * tx][p]);
    u32 hi = f2b(tile[2 * tx + 1][p]);
    *(u32*)(d + (size_t)(p0 + p) * 1024 + c0 + 2 * tx) = lo | (hi << 16);
  }
}

// fp32 -> bf16 pairwise convert (weights)
__global__ void __launch_bounds__(256)
cvt_pairs(const float* __restrict__ s, u16* __restrict__ d, int n2) {
  int i = blockIdx.x * blockDim.x + threadIdx.x;
  if (i < n2) {
    float2 v = ((const float2*)s)[i];
    ((u32*)d)[i] = (u32)f2b(v.x) | ((u32)f2b(v.y) << 16);
  }
}

__global__ void zero1k(u32* z) { z[threadIdx.x] = 0; }   // 256 thr -> 1KB zeros

// ---------------------------------------------------------------------------
// GEMM: C[p][o] = sum_c A[p][c] * B[o][c]   (A row-major [M][K], B [N][K])
// 128x128 tile, BK=64, 4 waves, 4x4 16x16x32 bf16 MFMA subtiles per wave.
// ---------------------------------------------------------------------------
template <int EPI>
__global__ void __launch_bounds__(256)
gemm_bf16(const u16* __restrict__ A, const u16* __restrict__ B, int K,
          u16* __restrict__ outb, int ldo,
          const float* __restrict__ bias0, const float* __restrict__ bias1,
          int split, float* __restrict__ outf, const float* __restrict__ xres) {
  __shared__ u16 lds[2 * 128 * 64];                  // 32 KB
  u16* Alds = lds;
  u16* Blds = lds + 128 * 64;

  const int tid = threadIdx.x;
  const int wave = tid >> 6, lane = tid & 63;
  const int quad = lane >> 4, col = lane & 15;
  const int wr = wave >> 1, wc = wave & 1;
  const int m0 = blockIdx.y * 128, n0 = blockIdx.x * 128;

  f32x4 acc[4][4] = {};

  int srow[4], skc[4];
#pragma unroll
  for (int i = 0; i < 4; ++i) {
    int c = i * 256 + tid;
    srow[i] = c >> 3;
    skc[i] = (c & 7) ^ (srow[i] & 7);                // swizzled source chunk
  }

  for (int k0 = 0; k0 < K; k0 += 64) {
    __syncthreads();
#pragma unroll
    for (int i = 0; i < 4; ++i)
      gl2lds16(A + (size_t)(m0 + srow[i]) * K + k0 + skc[i] * 8,
               Alds + (i * 256 + wave * 64) * 8);
#pragma unroll
    for (int i = 0; i < 4; ++i)
      gl2lds16(B + (size_t)(n0 + srow[i]) * K + k0 + skc[i] * 8,
               Blds + (i * 256 + wave * 64) * 8);
    __syncthreads();
#pragma unroll
    for (int ks = 0; ks < 2; ++ks) {
      bf16x8 af[4], bfr[4];
#pragma unroll
      for (int mt = 0; mt < 4; ++mt) {
        int row = wr * 64 + mt * 16 + col;
        int pos = (ks * 4 + quad) ^ (row & 7);
        af[mt] = *(const bf16x8*)(Alds + row * 64 + pos * 8);
      }
#pragma unroll
      for (int nt = 0; nt < 4; ++nt) {
        int row = wc * 64 + nt * 16 + col;
        int pos = (ks * 4 + quad) ^ (row & 7);
        bfr[nt] = *(const bf16x8*)(Blds + row * 64 + pos * 8);
      }
#pragma unroll
      for (int mt = 0; mt < 4; ++mt)
#pragma unroll
        for (int nt = 0; nt < 4; ++nt)
          acc[mt][nt] = __builtin_amdgcn_mfma_f32_16x16x32_bf16(
              af[mt], bfr[nt], acc[mt][nt], 0, 0, 0);
    }
  }

  if (EPI == 0) {
#pragma unroll
    for (int nt = 0; nt < 4; ++nt) {
      int n = n0 + wc * 64 + nt * 16 + col;
      float bv = (n < split) ? bias0[n] : bias1[n - split];
#pragma unroll
      for (int mt = 0; mt < 4; ++mt) {
        int mb = m0 + wr * 64 + mt * 16 + quad * 4;
#pragma unroll
        for (int r = 0; r < 4; ++r)
          outb[(size_t)(mb + r) * ldo + n] = f2b(acc[mt][nt][r] + bv);
      }
    }
  } else {
    int b = m0 / PIMG;                               // tile never crosses image
    int pb = m0 - b * PIMG + wr * 64;
    const float* xr = xres + (size_t)b * 1024 * PIMG;
    float* op = outf + (size_t)b * 1024 * PIMG;
#pragma unroll
    for (int nt = 0; nt < 4; ++nt) {
      int n = n0 + wc * 64 + nt * 16 + col;
      float bv = bias0[n];
#pragma unroll
      for (int mt = 0; mt < 4; ++mt) {
        int p = pb + mt * 16 + quad * 4;
        const float4 xv = *(const float4*)(xr + (size_t)n * PIMG + p);
        float4 o;
        o.x = acc[mt][nt][0] + bv + xv.x;
        o.y = acc[mt][nt][1] + bv + xv.y;
        o.z = acc[mt][nt][2] + bv + xv.z;
        o.w = acc[mt][nt][3] + bv + xv.w;
        *(float4*)(op + (size_t)n * PIMG + p) = o;
      }
    }
  }
}

// ---------------------------------------------------------------------------
// Correlation via MFMA. Block = 8x8 pixel patch (grid 12x12x4).
// A = theta[64 patch pixels][512], B = phi[16x16 window pixels][512];
// scores[m][n] -> (p, q) with q = (ny-py)*9 + (nx-px) when both in [0,8].
// OOB phi rows are staged from a zero page (score 0, matching the zero-pad
// reference; zeros still participate in softmax downstream).
// ---------------------------------------------------------------------------
__global__ void __launch_bounds__(256)
corr_mfma(const u16* __restrict__ theta, const u16* __restrict__ gphi,
          float* __restrict__ scores, const u16* __restrict__ zpage) {
  __shared__ u16 tlds[64 * 64];                      // 8 KB
  __shared__ u16 plds[256 * 64];                     // 32 KB
  const int tid = threadIdx.x;
  const int wave = tid >> 6, lane = tid & 63;
  const int quad = lane >> 4, col = lane & 15;
  const int h0 = blockIdx.y * 8, w0 = blockIdx.x * 8;
  const int pb = blockIdx.z * PIMG;

  const u16* tsrc[2];
#pragma unroll
  for (int i = 0; i < 2; ++i) {
    int u = i * 256 + tid;
    int row = u >> 3, c = u & 7;
    int p = pb + (h0 + (row >> 3)) * 96 + w0 + (row & 7);
    tsrc[i] = theta + (size_t)p * 512 + ((c ^ (row & 7)) * 8);
  }
  const u16* psrc[8];
#pragma unroll
  for (int i = 0; i < 8; ++i) {
    int u = i * 256 + tid;
    int row = u >> 3, c = u & 7;
    int hh = h0 - 4 + (row >> 4), w2 = w0 - 4 + (row & 15);
    const u16* s = ((unsigned)hh < 96u && (unsigned)w2 < 96u)
        ? gphi + (size_t)(pb + hh * 96 + w2) * 1024 + 512 : zpage;
    psrc[i] = s + ((c ^ (row & 7)) * 8);
  }

  f32x4 acc[4][4] = {};
  for (int k0 = 0; k0 < 512; k0 += 64) {
    __syncthreads();
#pragma unroll
    for (int i = 0; i < 2; ++i)
      gl2lds16(tsrc[i] + k0, tlds + (i * 256 + wave * 64) * 8);
#pragma unroll
    for (int i = 0; i < 8; ++i)
      gl2lds16(psrc[i] + k0, plds + (i * 256 + wave * 64) * 8);
    __syncthreads();
#pragma unroll
    for (int ks = 0; ks < 2; ++ks) {
      bf16x8 af[4], bfr[4];
#pragma unroll
      for (int mt = 0; mt < 4; ++mt) {
        int row = mt * 16 + col;
        int pos = (ks * 4 + quad) ^ (row & 7);
        af[mt] = *(const bf16x8*)(tlds + row * 64 + pos * 8);
      }
#pragma unroll
      for (int nt = 0; nt < 4; ++nt) {
        int row = (wave * 4 + nt) * 16 + col;
        int pos = (ks * 4 + quad) ^ (row & 7);
        bfr[nt] = *(const bf16x8*)(plds + row * 64 + pos * 8);
      }
#pragma unroll
      for (int mt = 0; mt < 4; ++mt)
#pragma unroll
        for (int nt = 0; nt < 4; ++nt)
          acc[mt][nt] = __builtin_amdgcn_mfma_f32_16x16x32_bf16(
              af[mt], bfr[nt], acc[mt][nt], 0, 0, 0);
    }
  }

#pragma unroll
  for (int nt = 0; nt < 4; ++nt) {
    int ny = wave * 4 + nt;                          // window row of this n
#pragma unroll
    for (int mt = 0; mt < 4; ++mt) {
#pragma unroll
      for (int r = 0; r < 4; ++r) {
        int m = mt * 16 + quad * 4 + r;
        int py = m >> 3, pxl = m & 7;
        int a = ny - py, b = col - pxl;
        if ((unsigned)a <= 8u && (unsigned)b <= 8u) {
          int p = pb + (h0 + py) * 96 + w0 + pxl;
          scores[(size_t)p * 81 + a * 9 + b] = acc[mt][nt][r] * SCALE;
        }
      }
    }
  }
}

// ---------------------------------------------------------------------------
// Softmax + assemble, patch-tiled. Block = 8x8 pixel patch.
// wl[64][81]: softmax weights (wave 0 computes serially, one pixel/lane).
// g patch (16x16 px) staged per 64-ch chunk into LDS pitch 72 u16 (+16B pad,
// pad slots fed from zero page to keep global_load_lds lane-ordering).
// Thread (m = tid>>2, sub = tid&3) accumulates 16 channels of pixel m.
// ---------------------------------------------------------------------------
__global__ void __launch_bounds__(256)
assemble2(const float* __restrict__ scores, const u16* __restrict__ gphi,
          u16* __restrict__ y, const u16* __restrict__ zpage) {
  __shared__ float wl[64 * 81];                      // 20736 B
  __shared__ u16 gl[256 * 72];                       // 36864 B
  const int tid = threadIdx.x;
  const int wave = tid >> 6;
  const int h0 = blockIdx.y * 8, w0 = blockIdx.x * 8;
  const int pb = blockIdx.z * PIMG;

  for (int idx = tid; idx < 5184; idx += 256) {
    int m = idx / 81, q = idx - m * 81;
    int p = pb + (h0 + (m >> 3)) * 96 + w0 + (m & 7);
    wl[idx] = scores[(size_t)p * 81 + q];
  }
  __syncthreads();
  if (tid < 64) {                                    // wave-0 softmax
    float* row = wl + tid * 81;
    float mx = row[0];
    for (int q = 1; q < 81; ++q) mx = fmaxf(mx, row[q]);
    float s = 0.f;
    for (int q = 0; q < 81; ++q) s += __expf(row[q] - mx);
    float inv = 1.0f / s;
    for (int q = 0; q < 81; ++q) row[q] = __expf(row[q] - mx) * inv;
  }

  // staging sources: 256 rows x 9 units (8 data + 1 pad) = 2304 units
  const u16* gsrc[9];
#pragma unroll
  for (int i = 0; i < 9; ++i) {
    int u = i * 256 + tid;
    int n = u / 9, ck = u - n * 9;
    int hh = h0 - 4 + (n >> 4), w2 = w0 - 4 + (n & 15);
    bool v = (ck < 8) && ((unsigned)hh < 96u) && ((unsigned)w2 < 96u);
    gsrc[i] = v ? gphi + (size_t)(pb + hh * 96 + w2) * 1024 + ck * 8 : zpage;
  }

  const int m = tid >> 2, sub = tid & 3;
  const int py = m >> 3, pxl = m & 7;
  const int nb = py * 16 + pxl;
  u16* yout = y + (size_t)(pb + (h0 + py) * 96 + w0 + pxl) * 512 + sub * 16;
  const float* wrow = wl + m * 81;

  for (int c0 = 0; c0 < 512; c0 += 64) {
    __syncthreads();                                 // also fences softmax
#pragma unroll
    for (int i = 0; i < 9; ++i)
      gl2lds16(gsrc[i] + c0, gl + (i * 256 + wave * 64) * 8);
    __syncthreads();
    float2 a2[8] = {};
    int q = 0;
    for (int a = 0; a < 9; ++a) {
      const u16* gra = gl + (nb + a * 16) * 72 + sub * 16;
#pragma unroll
      for (int b = 0; b < 9; ++b) {
        float wq = wrow[q]; ++q;
        const uint4 g0 = *(const uint4*)(gra + b * 72);
        const uint4 g1 = *(const uint4*)(gra + b * 72 + 8);
        a2[0].x += wq * bl(g0.x); a2[0].y += wq * bh(g0.x);
        a2[1].x += wq * bl(g0.y); a2[1].y += wq * bh(g0.y);
        a2[2].x += wq * bl(g0.z); a2[2].y += wq * bh(g0.z);
        a2[3].x += wq * bl(g0.w); a2[3].y += wq * bh(g0.w);
        a2[4].x += wq * bl(g1.x); a2[4].y += wq * bh(g1.x);
        a2[5].x += wq * bl(g1.y); a2[5].y += wq * bh(g1.y);
        a2[6].x += wq * bl(g1.z); a2[6].y += wq * bh(g1.z);
        a2[7].x += wq * bl(g1.w); a2[7].y += wq * bh(g1.w);
      }
    }
    uint4 o0, o1;
    o0.x = (u32)f2b(a2[0].x) | ((u32)f2b(a2[0].y) << 16);
    o0.y = (u32)f2b(a2[1].x) | ((u32)f2b(a2[1].y) << 16);
    o0.z = (u32)f2b(a2[2].x) | ((u32)f2b(a2[2].y) << 16);
    o0.w = (u32)f2b(a2[3].x) | ((u32)f2b(a2[3].y) << 16);
    o1.x = (u32)f2b(a2[4].x) | ((u32)f2b(a2[4].y) << 16);
    o1.y = (u32)f2b(a2[5].x) | ((u32)f2b(a2[5].y) << 16);
    o1.z = (u32)f2b(a2[6].x) | ((u32)f2b(a2[6].y) << 16);
    o1.w = (u32)f2b(a2[7].x) | ((u32)f2b(a2[7].y) << 16);
    *(uint4*)yout = o0;
    *(uint4*)(yout + 8) = o1;
    yout += 64;
  }
}

// ---------------------------------------------------------------------------
extern "C" void kernel_launch(void* const* d_in, const int* in_sizes, int n_in,
                              void* d_out, int out_size, void* d_ws,
                              size_t ws_size, hipStream_t stream) {
  const float* x    = (const float*)d_in[0];
  const float* xref = (const float*)d_in[1];
  const float* w_g  = (const float*)d_in[2];
  const float* b_g  = (const float*)d_in[3];
  const float* w_th = (const float*)d_in[4];
  const float* b_th = (const float*)d_in[5];
  const float* w_ph = (const float*)d_in[6];
  const float* b_ph = (const float*)d_in[7];
  const float* w_o  = (const float*)d_in[8];
  const float* b_o  = (const float*)d_in[9];

  char* ws = (char*)d_ws;
  // big holds x_ref^T (bf16), then x^T, then y — sequential lifetimes.
  u16*   big    = (u16*)(ws);                        // 75,497,472 B
  u16*   gphi   = (u16*)(ws + 75497472);             // 75,497,472 B
  u16*   theta  = (u16*)(ws + 150994944);            // 37,748,736 B
  float* scores = (float*)(ws + 188743680);          // 11,943,936 B
  u16*   wgp    = (u16*)(ws + 200687616);            //  2,097,152 B
  u16*   wth    = (u16*)(ws + 202784768);            //  1,048,576 B
  u16*   wout   = (u16*)(ws + 203833344);            //  1,048,576 B
  // zero page: carved inside `big` past y's 37.75MB live range (48MB offset);
  // zeroed after the last full overwrite of big (x transpose).
  u16*   zpage  = big + 24 * 1024 * 1024;            // 1 KB zeros

  // weights -> bf16 (w_g & w_phi stacked into one [1024][1024] B-operand)
  cvt_pairs<<<1024, 256, 0, stream>>>(w_g, wgp, 262144);
  cvt_pairs<<<1024, 256, 0, stream>>>(w_ph, wgp + 524288, 262144);
  cvt_pairs<<<1024, 256, 0, stream>>>(w_th, wth, 262144);
  cvt_pairs<<<1024, 256, 0, stream>>>(w_o, wout, 262144);

  dim3 tb(32, 8);
  // x_ref -> [p][c] bf16, then g|phi = xref^T x [w_g;w_phi]^T  (N=1024)
  transpose_cvt<<<dim3(288, 16, 4), tb, 0, stream>>>(xref, big);
  gemm_bf16<0><<<dim3(8, 288), 256, 0, stream>>>(big, wgp, 1024, gphi, 1024,
                                                 b_g, b_ph, 512, nullptr,
                                                 nullptr);
  // x -> [p][c] bf16 (reuses big), then theta (N=512)
  transpose_cvt<<<dim3(288, 16, 4), tb, 0, stream>>>(x, big);
  gemm_bf16<0><<<dim3(4, 288), 256, 0, stream>>>(big, wth, 1024, theta, 512,
                                                 b_th, b_th, 512, nullptr,
                                                 nullptr);

  zero1k<<<1, 256, 0, stream>>>((u32*)zpage);

  corr_mfma<<<dim3(12, 12, 4), 256, 0, stream>>>(theta, gphi, scores, zpage);
  assemble2<<<dim3(12, 12, 4), 256, 0, stream>>>(scores, gphi, big /* y */,
                                                 zpage);

  // out = x + y x w_out^T + b_out   (fp32, fused residual epilogue)
  gemm_bf16<1><<<dim3(8, 288), 256, 0, stream>>>(big, wout, 512, nullptr, 0,
                                                 b_o, b_o, 1024, (float*)d_out,
                                                 x);
}